// Round 2
// baseline (3071.163 us; speedup 1.0000x reference)
//
#include <hip/hip_runtime.h>
#include <math.h>

// Problem constants
#define BB 2
#define NDIM 64      // D = H = W = 64
#define CC 128       // channels
#define WR 33        // rfft bins along W
#define NBLK 8
#define BSZ 16

static constexpr float LAM = 0.01f;       // softshrink lambda
static constexpr float ORTHO = 1.0f / 512.0f;  // 1/sqrt(64^3)
static constexpr float TWO_PI_64 = 6.28318530717958647692f / 64.0f;

// LDS row stride (in float2) for one 64-elem transform (LDS-based FFT kernels)
#define LROW 66

// ---- compile-time twiddle table: c[t]=cos(2*pi*t/64), s[t]=sin(2*pi*t/64)
struct TwTab {
  float c[64], s[64];
  constexpr TwTab() : c(), s() {
    const double PI = 3.14159265358979323846;
    for (int t = 0; t < 64; t++) {
      double a = 2.0 * PI * (double)t / 64.0;
      if (a > PI) a -= 2.0 * PI;  // reduce to [-pi, pi]
      double x2 = a * a;
      double sv = a, tv = a;
      for (int i = 1; i < 14; i++) { tv *= -x2 / (double)((2 * i) * (2 * i + 1)); sv += tv; }
      double cv = 1.0, tc = 1.0;
      for (int i = 1; i < 14; i++) { tc *= -x2 / (double)((2 * i - 1) * (2 * i)); cv += tc; }
      c[t] = (float)cv;
      s[t] = (float)sv;
    }
  }
};
constexpr TwTab TW{};

__device__ inline float2 cmulf(float2 a, float2 b) {
    return make_float2(a.x * b.x - a.y * b.y, a.x * b.y + a.y * b.x);
}

// bf16 pack/unpack (RNE)
__device__ inline unsigned pack_bf16(float a, float b) {
    unsigned ua = __float_as_uint(a), ub = __float_as_uint(b);
    ua += 0x7fffu + ((ua >> 16) & 1u);
    ub += 0x7fffu + ((ub >> 16) & 1u);
    return (ua >> 16) | (ub & 0xffff0000u);
}
__device__ inline float bf_lo(unsigned u) { return __uint_as_float(u << 16); }
__device__ inline float bf_hi(unsigned u) { return __uint_as_float(u & 0xffff0000u); }

// Naive fully-unrolled 8-point DFT. DIR = -1 forward, +1 inverse.
template <int DIR>
__device__ inline void dft8(const float2 v[8], float2 y[8]) {
    const float s = 0.70710678118654752440f;
    float2 T[8];
    T[0] = make_float2(1.f, 0.f);
    T[1] = make_float2(s, DIR * s);
    T[2] = make_float2(0.f, DIR * 1.f);
    T[3] = make_float2(-s, DIR * s);
    T[4] = make_float2(-1.f, 0.f);
    T[5] = make_float2(-s, -DIR * s);
    T[6] = make_float2(0.f, -DIR * 1.f);
    T[7] = make_float2(s, -DIR * s);
#pragma unroll
    for (int k = 0; k < 8; k++) {
        float2 acc = v[0];
#pragma unroll
        for (int j = 1; j < 8; j++) {
            float2 t = T[(j * k) & 7];
            acc.x += v[j].x * t.x - v[j].y * t.y;
            acc.y += v[j].x * t.y + v[j].y * t.x;
        }
        y[k] = acc;
    }
}

// ---- 64-pt FFT fully in registers (radix 8x8). Input natural order r[n].
// Output: X[k] sits at r[8*(k&7) + (k>>3)] (digit-reversed storage).
template <int DIR>
__device__ inline void fft64_reg(float2 r[64]) {
    float2 v[8], y[8];
#pragma unroll
    for (int n2 = 0; n2 < 8; n2++) {
#pragma unroll
        for (int n1 = 0; n1 < 8; n1++) v[n1] = r[8 * n1 + n2];
        dft8<DIR>(v, y);
#pragma unroll
        for (int k1 = 1; k1 < 8; k1++) {
            const int t = (k1 * n2) & 63;
            float2 w = make_float2(TW.c[t], (float)DIR * TW.s[t]);
            y[k1] = cmulf(y[k1], w);
        }
#pragma unroll
        for (int k1 = 0; k1 < 8; k1++) r[8 * k1 + n2] = y[k1];
    }
#pragma unroll
    for (int k1 = 0; k1 < 8; k1++) {
#pragma unroll
        for (int n2 = 0; n2 < 8; n2++) v[n2] = r[8 * k1 + n2];
        dft8<DIR>(v, y);
#pragma unroll
        for (int k2 = 0; k2 < 8; k2++) r[8 * k1 + k2] = y[k2];
    }
}

// 64-pt FFT on 64 contiguous float2 in LDS, cooperatively by 8 threads p=0..7.
template <int DIR>
__device__ inline void fft64_lds(float2* base, int p) {
    float2 v[8], a[8];
#pragma unroll
    for (int n1 = 0; n1 < 8; n1++) v[n1] = base[8 * n1 + p];
    dft8<DIR>(v, a);
#pragma unroll
    for (int k1 = 1; k1 < 8; k1++) {
        float ang = (float)DIR * TWO_PI_64 * (float)(p * k1);
        float sn, cs;
        __sincosf(ang, &sn, &cs);
        a[k1] = cmulf(a[k1], make_float2(cs, sn));
    }
#pragma unroll
    for (int k1 = 0; k1 < 8; k1++) base[8 * k1 + p] = a[k1];
    __syncthreads();
    float2 u[8], y[8];
#pragma unroll
    for (int n2 = 0; n2 < 8; n2++) u[n2] = base[8 * p + n2];
    dft8<DIR>(u, y);
    __syncthreads();
#pragma unroll
    for (int k2 = 0; k2 < 8; k2++) base[8 * k2 + p] = y[k2];  // k = p + 8*k2
}

// ---------------- Pass 1: rfft along W. x (B,D,H,W,C) f32 -> buf (B,D,H,WR,C) c64
__global__ __launch_bounds__(256) void k_rfft_w(const float* __restrict__ x,
                                                float2* __restrict__ buf) {
    __shared__ float2 lds[32 * LROW];
    const int t = threadIdx.x;
    const size_t bdh = blockIdx.x;
    const float* xp = x + bdh * (size_t)(NDIM * CC);
    float2* op = buf + bdh * (size_t)(WR * CC);
    for (int chunk = 0; chunk < 4; chunk++) {
        const int c0 = chunk * 32;
#pragma unroll
        for (int k = 0; k < 8; k++) {
            int i = k * 256 + t;
            int c = i & 31, w = i >> 5;
            float vv = xp[(size_t)w * CC + c0 + c] * ORTHO;
            lds[c * LROW + w] = make_float2(vv, 0.f);
        }
        __syncthreads();
        fft64_lds<-1>(&lds[(t >> 3) * LROW], t & 7);
        __syncthreads();
        for (int i = t; i < WR * 32; i += 256) {
            int c = i & 31, kk = i >> 5;
            op[(size_t)kk * CC + c0 + c] = lds[c * LROW + kk];
        }
        __syncthreads();
    }
}

// ---------------- Passes 2,6: in-place complex FFT along a strided axis (H).
template <int DIR>
__global__ __launch_bounds__(256) void k_fft_axis(float2* __restrict__ buf, int outerB,
                                                  long sA, long sB, long sAxis) {
    __shared__ float2 lds[32 * LROW];
    const int t = threadIdx.x;
    const long a = blockIdx.x / outerB;
    const long ob = blockIdx.x % outerB;
    float2* p0 = buf + a * sA + ob * sB;
    for (int chunk = 0; chunk < 4; chunk++) {
        const int c0 = chunk * 32;
#pragma unroll
        for (int k = 0; k < 8; k++) {
            int i = k * 256 + t;
            int c = i & 31, n = i >> 5;
            lds[c * LROW + n] = p0[(long)n * sAxis + c0 + c];
        }
        __syncthreads();
        fft64_lds<DIR>(&lds[(t >> 3) * LROW], t & 7);
        __syncthreads();
#pragma unroll
        for (int k = 0; k < 8; k++) {
            int i = k * 256 + t;
            int c = i & 31, n = i >> 5;
            p0[(long)n * sAxis + c0 + c] = lds[c * LROW + n];
        }
        __syncthreads();
    }
}

// ---------------- Fused: FFT-D (fwd) -> block-diag complex MLP+softshrink -> iFFT-D.
// One block per (b, h, wr). 128 threads. Spectrum staged in LDS as packed bf16.
__global__ __launch_bounds__(128) void k_fft_d_mlp(float2* __restrict__ buf,
                                                   const float* __restrict__ w1,
                                                   const float* __restrict__ b1,
                                                   const float* __restrict__ w2,
                                                   const float* __restrict__ b2) {
    __shared__ unsigned S[CC * 65];  // [c][k], pitch 65 u32 (bank-friendly)
    const int tid = threadIdx.x;
    int id = blockIdx.x;
    const int wr = id % WR; id /= WR;
    const int h = id % NDIM; id /= NDIM;
    const int b = id;
    const long S_H = (long)WR * CC;
    const long S_D = (long)NDIM * S_H;
    const long S_B = (long)NDIM * S_D;
    float2* p0 = buf + (long)b * S_B + (long)h * S_H + (long)wr * CC;

    // phase 1: forward FFT along D, one channel line per thread (c = tid)
    {
        const int c = tid;
        float2 r[64];
#pragma unroll
        for (int d = 0; d < 64; d++) r[d] = p0[(long)d * S_D + c];
        fft64_reg<-1>(r);
#pragma unroll
        for (int k = 0; k < 64; k++) {
            float2 xv = r[8 * (k & 7) + (k >> 3)];
            S[c * 65 + k] = pack_bf16(xv.x, xv.y);
        }
    }
    __syncthreads();

    // phase 2: MLP. lane = frequency point (d-index); wave wv handles blks 4wv..4wv+3
    {
        const int pt = tid & 63;
        const int wv = tid >> 6;
#pragma unroll 1
        for (int bq = 0; bq < 4; bq++) {
            const int blk = wv * 4 + bq;
            const float* W1r = w1 + blk * 256;
            const float* W1i = w1 + 2048 + blk * 256;
            const float* W2r = w2 + blk * 256;
            const float* W2i = w2 + 2048 + blk * 256;
            float xr[16], xi[16];
#pragma unroll
            for (int i = 0; i < 16; i++) {
                unsigned u = S[(blk * 16 + i) * 65 + pt];
                xr[i] = bf_lo(u);
                xi[i] = bf_hi(u);
            }
            float o1r[16], o1i[16];
#pragma unroll
            for (int o = 0; o < 16; o++) {
                float sr = b1[blk * 16 + o], si = b1[128 + blk * 16 + o];
#pragma unroll
                for (int i = 0; i < 16; i++) {
                    float wr_ = W1r[i * 16 + o], wi_ = W1i[i * 16 + o];
                    sr += xr[i] * wr_ - xi[i] * wi_;
                    si += xi[i] * wr_ + xr[i] * wi_;
                }
                o1r[o] = fmaxf(sr, 0.f);
                o1i[o] = fmaxf(si, 0.f);
            }
#pragma unroll
            for (int o = 0; o < 16; o++) {
                float sr = b2[blk * 16 + o], si = b2[128 + blk * 16 + o];
#pragma unroll
                for (int i = 0; i < 16; i++) {
                    float wr_ = W2r[i * 16 + o], wi_ = W2i[i * 16 + o];
                    sr += o1r[i] * wr_ - o1i[i] * wi_;
                    si += o1i[i] * wr_ + o1r[i] * wi_;
                }
                sr = (sr > LAM) ? (sr - LAM) : ((sr < -LAM) ? (sr + LAM) : 0.f);
                si = (si > LAM) ? (si - LAM) : ((si < -LAM) ? (si + LAM) : 0.f);
                S[(blk * 16 + o) * 65 + pt] = pack_bf16(sr, si);
            }
        }
    }
    __syncthreads();

    // phase 3: inverse FFT along D, write back (no scaling; ortho handled at ends)
    {
        const int c = tid;
        float2 r[64];
#pragma unroll
        for (int k = 0; k < 64; k++) {
            unsigned u = S[c * 65 + k];
            r[k] = make_float2(bf_lo(u), bf_hi(u));
        }
        fft64_reg<1>(r);
#pragma unroll
        for (int d = 0; d < 64; d++) {
            p0[(long)d * S_D + c] = r[8 * (d & 7) + (d >> 3)];
        }
    }
}

// ---------------- Pass 7: irfft along W + residual.
__global__ __launch_bounds__(256) void k_irfft_w(const float2* __restrict__ buf,
                                                 const float* __restrict__ x,
                                                 float* __restrict__ out) {
    __shared__ float2 lds[32 * LROW];
    const int t = threadIdx.x;
    const size_t bdh = blockIdx.x;
    const float2* ip = buf + bdh * (size_t)(WR * CC);
    const float* xp = x + bdh * (size_t)(NDIM * CC);
    float* op = out + bdh * (size_t)(NDIM * CC);
    for (int chunk = 0; chunk < 4; chunk++) {
        const int c0 = chunk * 32;
        for (int i = t; i < WR * 32; i += 256) {
            int c = i & 31, kk = i >> 5;
            lds[c * LROW + kk] = ip[(size_t)kk * CC + c0 + c];
        }
        __syncthreads();
        for (int i = t; i < 31 * 32; i += 256) {
            int c = i & 31, kk = 33 + (i >> 5);
            float2 v = lds[c * LROW + (64 - kk)];
            lds[c * LROW + kk] = make_float2(v.x, -v.y);
        }
        __syncthreads();
        fft64_lds<1>(&lds[(t >> 3) * LROW], t & 7);
        __syncthreads();
#pragma unroll
        for (int k = 0; k < 8; k++) {
            int i = k * 256 + t;
            int c = i & 31, w = i >> 5;
            size_t gi = (size_t)w * CC + c0 + c;
            op[gi] = lds[c * LROW + w].x * ORTHO + xp[gi];
        }
        __syncthreads();
    }
}

extern "C" void kernel_launch(void* const* d_in, const int* in_sizes, int n_in,
                              void* d_out, int out_size, void* d_ws, size_t ws_size,
                              hipStream_t stream) {
    const float* x = (const float*)d_in[0];
    const float* w1 = (const float*)d_in[1];
    const float* b1 = (const float*)d_in[2];
    const float* w2 = (const float*)d_in[3];
    const float* b2 = (const float*)d_in[4];
    float* out = (float*)d_out;
    float2* buf = (float2*)d_ws;  // B*D*H*WR*C float2 = 553,648,128 bytes

    // strides in float2 units
    const long S_WR = CC;               // 128
    const long S_H = (long)WR * CC;     // 4224
    const long S_D = (long)NDIM * S_H;  // 270336

    // 1) rfft along W
    k_rfft_w<<<BB * NDIM * NDIM, 256, 0, stream>>>(x, buf);
    // 2) FFT along H
    k_fft_axis<-1><<<BB * NDIM * WR, 256, 0, stream>>>(buf, WR, S_D, S_WR, S_H);
    // 3+4+5) fused FFT-D -> MLP -> iFFT-D
    k_fft_d_mlp<<<BB * NDIM * WR, 128, 0, stream>>>(buf, w1, b1, w2, b2);
    // 6) inverse FFT along H
    k_fft_axis<1><<<BB * NDIM * WR, 256, 0, stream>>>(buf, WR, S_D, S_WR, S_H);
    // 7) irfft along W + residual
    k_irfft_w<<<BB * NDIM * NDIM, 256, 0, stream>>>(buf, x, out);
}

// Round 3
// 1546.629 us; speedup vs baseline: 1.9857x; 1.9857x over previous
//
#include <hip/hip_runtime.h>
#include <math.h>

// Problem constants
#define BB 2
#define NDIM 64      // D = H = W = 64
#define CC 128       // channels
#define WR 33        // rfft bins along W
#define NBLK 8
#define BSZ 16

static constexpr float LAM = 0.01f;            // softshrink lambda
static constexpr float ORTHO = 1.0f / 512.0f;  // 1/sqrt(64^3)
static constexpr float TWO_PI_64 = 6.28318530717958647692f / 64.0f;

// LDS row stride (in float2) for one 64-elem transform: pad 64 -> 66.
#define LROW 66

__device__ inline float2 cmulf(float2 a, float2 b) {
    return make_float2(a.x * b.x - a.y * b.y, a.x * b.y + a.y * b.x);
}

// Naive fully-unrolled 8-point DFT. DIR = -1 forward, +1 inverse.
template <int DIR>
__device__ inline void dft8(const float2 v[8], float2 y[8]) {
    const float s = 0.70710678118654752440f;
    float2 T[8];
    T[0] = make_float2(1.f, 0.f);
    T[1] = make_float2(s, DIR * s);
    T[2] = make_float2(0.f, DIR * 1.f);
    T[3] = make_float2(-s, DIR * s);
    T[4] = make_float2(-1.f, 0.f);
    T[5] = make_float2(-s, -DIR * s);
    T[6] = make_float2(0.f, -DIR * 1.f);
    T[7] = make_float2(s, -DIR * s);
#pragma unroll
    for (int k = 0; k < 8; k++) {
        float2 acc = v[0];
#pragma unroll
        for (int j = 1; j < 8; j++) {
            float2 t = T[(j * k) & 7];
            acc.x += v[j].x * t.x - v[j].y * t.y;
            acc.y += v[j].x * t.y + v[j].y * t.x;
        }
        y[k] = acc;
    }
}

// 64-pt FFT on 64 contiguous float2 in LDS (base), cooperatively by 8 threads
// p = 0..7. All accesses stay within this row. Result in natural order.
// Caller must __syncthreads() after this before other threads consume results.
template <int DIR>
__device__ inline void fft64_lds(float2* base, int p) {
    float2 v[8], a[8];
#pragma unroll
    for (int n1 = 0; n1 < 8; n1++) v[n1] = base[8 * n1 + p];
    dft8<DIR>(v, a);
#pragma unroll
    for (int k1 = 1; k1 < 8; k1++) {
        float ang = (float)DIR * TWO_PI_64 * (float)(p * k1);
        float sn, cs;
        __sincosf(ang, &sn, &cs);
        a[k1] = cmulf(a[k1], make_float2(cs, sn));
    }
#pragma unroll
    for (int k1 = 0; k1 < 8; k1++) base[8 * k1 + p] = a[k1];
    __syncthreads();
    float2 u[8], y[8];
#pragma unroll
    for (int n2 = 0; n2 < 8; n2++) u[n2] = base[8 * p + n2];
    dft8<DIR>(u, y);
    __syncthreads();
#pragma unroll
    for (int k2 = 0; k2 < 8; k2++) base[8 * k2 + p] = y[k2];  // holds X[p + 8*k2]
}

// ---------------- Pass 1: rfft along W. x (B,D,H,W,C) f32 -> buf (B,D,H,WR,C) c64
__global__ __launch_bounds__(256) void k_rfft_w(const float* __restrict__ x,
                                                float2* __restrict__ buf) {
    __shared__ float2 lds[32 * LROW];
    const int t = threadIdx.x;
    const size_t bdh = blockIdx.x;
    const float* xp = x + bdh * (size_t)(NDIM * CC);
    float2* op = buf + bdh * (size_t)(WR * CC);
    for (int chunk = 0; chunk < 4; chunk++) {
        const int c0 = chunk * 32;
#pragma unroll
        for (int k = 0; k < 8; k++) {
            int i = k * 256 + t;
            int c = i & 31, w = i >> 5;
            float vv = xp[(size_t)w * CC + c0 + c] * ORTHO;
            lds[c * LROW + w] = make_float2(vv, 0.f);
        }
        __syncthreads();
        fft64_lds<-1>(&lds[(t >> 3) * LROW], t & 7);
        __syncthreads();
        for (int i = t; i < WR * 32; i += 256) {
            int c = i & 31, kk = i >> 5;
            op[(size_t)kk * CC + c0 + c] = lds[c * LROW + kk];
        }
        __syncthreads();
    }
}

// ---------------- Passes 2,6: in-place complex FFT along H (strided axis).
template <int DIR>
__global__ __launch_bounds__(256) void k_fft_axis(float2* __restrict__ buf, int outerB,
                                                  long sA, long sB, long sAxis) {
    __shared__ float2 lds[32 * LROW];
    const int t = threadIdx.x;
    const long a = blockIdx.x / outerB;
    const long ob = blockIdx.x % outerB;
    float2* p0 = buf + a * sA + ob * sB;
    for (int chunk = 0; chunk < 4; chunk++) {
        const int c0 = chunk * 32;
#pragma unroll
        for (int k = 0; k < 8; k++) {
            int i = k * 256 + t;
            int c = i & 31, n = i >> 5;
            lds[c * LROW + n] = p0[(long)n * sAxis + c0 + c];
        }
        __syncthreads();
        fft64_lds<DIR>(&lds[(t >> 3) * LROW], t & 7);
        __syncthreads();
#pragma unroll
        for (int k = 0; k < 8; k++) {
            int i = k * 256 + t;
            int c = i & 31, n = i >> 5;
            p0[(long)n * sAxis + c0 + c] = lds[c * LROW + n];
        }
        __syncthreads();
    }
}

// ---------------- Fused: FFT-D -> block-diag complex MLP + softshrink -> iFFT-D.
// One block per (b, h, wr, ch-half). 256 threads, 64 channels x 64 d in LDS f32.
__global__ __launch_bounds__(256) void k_dmlp(float2* __restrict__ buf,
                                              const float* __restrict__ w1,
                                              const float* __restrict__ b1,
                                              const float* __restrict__ w2,
                                              const float* __restrict__ b2) {
    __shared__ float2 S[64 * LROW];  // [c local 0..63][d 0..63], pitch 66
    const int t = threadIdx.x;
    int id = blockIdx.x;
    const int half = id & 1; id >>= 1;
    const int wr = id % WR; id /= WR;
    const int h = id % NDIM; id /= NDIM;
    const int b = id;
    const long S_H = (long)WR * CC;
    const long S_D = (long)NDIM * S_H;
    const long S_B = (long)NDIM * S_D;
    float2* p0 = buf + (long)b * S_B + (long)h * S_H + (long)wr * CC + half * 64;

    // load: 64 ch x 64 d. lane -> channel (contiguous 512B per instr)
    const int lc = t & 63;
    const int d0 = t >> 6;
#pragma unroll
    for (int k = 0; k < 16; k++) {
        int d = d0 + 4 * k;
        S[lc * LROW + d] = p0[(long)d * S_D + lc];
    }
    __syncthreads();

    // forward FFT along d for each channel row (32 groups of 8 threads, 2 iters)
#pragma unroll 1
    for (int it = 0; it < 2; it++) {
        fft64_lds<-1>(&S[((t >> 3) + 32 * it) * LROW], t & 7);
        __syncthreads();
    }

    // MLP: thread -> (freq point pt, local block bl). Weights via scalar path.
    {
        const int pt = t & 63;
        const int bl = t >> 6;                                    // 0..3
        const int blk = __builtin_amdgcn_readfirstlane(half * 4 + bl);  // 0..7, wave-uniform
        const float* W1r = w1 + (size_t)blk * 256;
        const float* W1i = w1 + 2048 + (size_t)blk * 256;
        const float* W2r = w2 + (size_t)blk * 256;
        const float* W2i = w2 + 2048 + (size_t)blk * 256;

        float xr[16], xi[16];
#pragma unroll
        for (int i = 0; i < 16; i++) {
            float2 v = S[(bl * 16 + i) * LROW + pt];
            xr[i] = v.x;
            xi[i] = v.y;
        }
        float o1r[16], o1i[16];
#pragma unroll
        for (int o = 0; o < 16; o++) {
            o1r[o] = b1[blk * 16 + o];
            o1i[o] = b1[128 + blk * 16 + o];
        }
#pragma unroll
        for (int i = 0; i < 16; i++) {
#pragma unroll
            for (int o = 0; o < 16; o++) {
                float wr_ = W1r[i * 16 + o], wi_ = W1i[i * 16 + o];
                o1r[o] += xr[i] * wr_ - xi[i] * wi_;
                o1i[o] += xi[i] * wr_ + xr[i] * wi_;
            }
        }
#pragma unroll
        for (int o = 0; o < 16; o++) {
            o1r[o] = fmaxf(o1r[o], 0.f);
            o1i[o] = fmaxf(o1i[o], 0.f);
        }
        float o2r[16], o2i[16];
#pragma unroll
        for (int o = 0; o < 16; o++) {
            o2r[o] = b2[blk * 16 + o];
            o2i[o] = b2[128 + blk * 16 + o];
        }
#pragma unroll
        for (int i = 0; i < 16; i++) {
#pragma unroll
            for (int o = 0; o < 16; o++) {
                float wr_ = W2r[i * 16 + o], wi_ = W2i[i * 16 + o];
                o2r[o] += o1r[i] * wr_ - o1i[i] * wi_;
                o2i[o] += o1i[i] * wr_ + o1r[i] * wi_;
            }
        }
#pragma unroll
        for (int o = 0; o < 16; o++) {
            float sr = o2r[o], si = o2i[o];
            sr = (sr > LAM) ? (sr - LAM) : ((sr < -LAM) ? (sr + LAM) : 0.f);
            si = (si > LAM) ? (si - LAM) : ((si < -LAM) ? (si + LAM) : 0.f);
            S[(bl * 16 + o) * LROW + pt] = make_float2(sr, si);
        }
    }
    __syncthreads();

    // inverse FFT along d, then store back (no scaling here)
#pragma unroll 1
    for (int it = 0; it < 2; it++) {
        fft64_lds<1>(&S[((t >> 3) + 32 * it) * LROW], t & 7);
        __syncthreads();
    }
#pragma unroll
    for (int k = 0; k < 16; k++) {
        int d = d0 + 4 * k;
        p0[(long)d * S_D + lc] = S[lc * LROW + d];
    }
}

// ---------------- Pass 7: irfft along W + residual.
__global__ __launch_bounds__(256) void k_irfft_w(const float2* __restrict__ buf,
                                                 const float* __restrict__ x,
                                                 float* __restrict__ out) {
    __shared__ float2 lds[32 * LROW];
    const int t = threadIdx.x;
    const size_t bdh = blockIdx.x;
    const float2* ip = buf + bdh * (size_t)(WR * CC);
    const float* xp = x + bdh * (size_t)(NDIM * CC);
    float* op = out + bdh * (size_t)(NDIM * CC);
    for (int chunk = 0; chunk < 4; chunk++) {
        const int c0 = chunk * 32;
        for (int i = t; i < WR * 32; i += 256) {
            int c = i & 31, kk = i >> 5;
            lds[c * LROW + kk] = ip[(size_t)kk * CC + c0 + c];
        }
        __syncthreads();
        for (int i = t; i < 31 * 32; i += 256) {
            int c = i & 31, kk = 33 + (i >> 5);
            float2 v = lds[c * LROW + (64 - kk)];
            lds[c * LROW + kk] = make_float2(v.x, -v.y);
        }
        __syncthreads();
        fft64_lds<1>(&lds[(t >> 3) * LROW], t & 7);
        __syncthreads();
#pragma unroll
        for (int k = 0; k < 8; k++) {
            int i = k * 256 + t;
            int c = i & 31, w = i >> 5;
            size_t gi = (size_t)w * CC + c0 + c;
            op[gi] = lds[c * LROW + w].x * ORTHO + xp[gi];
        }
        __syncthreads();
    }
}

extern "C" void kernel_launch(void* const* d_in, const int* in_sizes, int n_in,
                              void* d_out, int out_size, void* d_ws, size_t ws_size,
                              hipStream_t stream) {
    const float* x = (const float*)d_in[0];
    const float* w1 = (const float*)d_in[1];
    const float* b1 = (const float*)d_in[2];
    const float* w2 = (const float*)d_in[3];
    const float* b2 = (const float*)d_in[4];
    float* out = (float*)d_out;
    float2* buf = (float2*)d_ws;  // B*D*H*WR*C float2 = 553,648,128 bytes

    // strides in float2 units
    const long S_WR = CC;               // 128
    const long S_H = (long)WR * CC;     // 4224
    const long S_D = (long)NDIM * S_H;  // 270336

    // 1) rfft along W
    k_rfft_w<<<BB * NDIM * NDIM, 256, 0, stream>>>(x, buf);
    // 2) FFT along H
    k_fft_axis<-1><<<BB * NDIM * WR, 256, 0, stream>>>(buf, WR, S_D, S_WR, S_H);
    // 3+4+5) fused FFT-D -> MLP -> iFFT-D (LDS-cooperative, 2 ch-halves per point)
    k_dmlp<<<BB * NDIM * WR * 2, 256, 0, stream>>>(buf, w1, b1, w2, b2);
    // 6) inverse FFT along H
    k_fft_axis<1><<<BB * NDIM * WR, 256, 0, stream>>>(buf, WR, S_D, S_WR, S_H);
    // 7) irfft along W + residual
    k_irfft_w<<<BB * NDIM * NDIM, 256, 0, stream>>>(buf, x, out);
}

// Round 4
// 1345.622 us; speedup vs baseline: 2.2823x; 1.1494x over previous
//
#include <hip/hip_runtime.h>
#include <math.h>

// Problem constants
#define BB 2
#define NDIM 64      // D = H = W = 64
#define CC 128       // channels
#define WR 33        // rfft bins along W
#define NBLK 8
#define BSZ 16

static constexpr float LAM = 0.01f;            // softshrink lambda
static constexpr float ORTHO = 1.0f / 512.0f;  // 1/sqrt(64^3)
static constexpr float TWO_PI_64 = 6.28318530717958647692f / 64.0f;

// LDS row stride (in float2) for one 64-elem transform: pad 64 -> 66.
#define LROW 66

// Spectrum element strides (uint32 units), layout (b, d, h, wr, c)
#define S_WRs 128L
#define S_Hs 4224L      // 33*128
#define S_Ds 270336L    // 64*4224
#define S_Bs 17301504L  // 64*270336

__device__ inline float2 cmulf(float2 a, float2 b) {
    return make_float2(a.x * b.x - a.y * b.y, a.x * b.y + a.y * b.x);
}

// bf16 pack/unpack (RNE). re in low 16, im in high 16.
__device__ inline unsigned pack_c(float2 v) {
    unsigned ua = __float_as_uint(v.x), ub = __float_as_uint(v.y);
    ua += 0x7fffu + ((ua >> 16) & 1u);
    ub += 0x7fffu + ((ub >> 16) & 1u);
    return (ua >> 16) | (ub & 0xffff0000u);
}
__device__ inline float2 unpack_c(unsigned u) {
    return make_float2(__uint_as_float(u << 16), __uint_as_float(u & 0xffff0000u));
}

// Naive fully-unrolled 8-point DFT. DIR = -1 forward, +1 inverse.
template <int DIR>
__device__ inline void dft8(const float2 v[8], float2 y[8]) {
    const float s = 0.70710678118654752440f;
    float2 T[8];
    T[0] = make_float2(1.f, 0.f);
    T[1] = make_float2(s, DIR * s);
    T[2] = make_float2(0.f, DIR * 1.f);
    T[3] = make_float2(-s, DIR * s);
    T[4] = make_float2(-1.f, 0.f);
    T[5] = make_float2(-s, -DIR * s);
    T[6] = make_float2(0.f, -DIR * 1.f);
    T[7] = make_float2(s, -DIR * s);
#pragma unroll
    for (int k = 0; k < 8; k++) {
        float2 acc = v[0];
#pragma unroll
        for (int j = 1; j < 8; j++) {
            float2 t = T[(j * k) & 7];
            acc.x += v[j].x * t.x - v[j].y * t.y;
            acc.y += v[j].x * t.y + v[j].y * t.x;
        }
        y[k] = acc;
    }
}

// Per-thread twiddles for its p = t&7: tw[k1-1] = (cos, sin)(+2*pi*p*k1/64)
__device__ inline void make_tw(int p, float2 tw[7]) {
#pragma unroll
    for (int k1 = 1; k1 < 8; k1++) {
        float ang = TWO_PI_64 * (float)(p * k1);
        float sn, cs;
        __sincosf(ang, &sn, &cs);
        tw[k1 - 1] = make_float2(cs, sn);
    }
}

// 64-pt FFT on 64 contiguous float2 in LDS (base), cooperatively by 8 threads
// p = 0..7. Natural order in, natural order out.
// Caller must __syncthreads() after this before other threads consume results.
template <int DIR>
__device__ inline void fft64_lds(float2* base, int p, const float2 tw[7]) {
    float2 v[8], a[8];
#pragma unroll
    for (int n1 = 0; n1 < 8; n1++) v[n1] = base[8 * n1 + p];
    dft8<DIR>(v, a);
#pragma unroll
    for (int k1 = 1; k1 < 8; k1++) {
        float2 w = make_float2(tw[k1 - 1].x, (float)DIR * tw[k1 - 1].y);
        a[k1] = cmulf(a[k1], w);
    }
#pragma unroll
    for (int k1 = 0; k1 < 8; k1++) base[8 * k1 + p] = a[k1];
    __syncthreads();
    float2 u[8], y[8];
#pragma unroll
    for (int n2 = 0; n2 < 8; n2++) u[n2] = base[8 * p + n2];
    dft8<DIR>(u, y);
    __syncthreads();
#pragma unroll
    for (int k2 = 0; k2 < 8; k2++) base[8 * k2 + p] = y[k2];  // holds X[p + 8*k2]
}

// ---------------- Pass 1: rfft along W. x f32 -> buf (b,d,h,wr,c) packed bf16
__global__ __launch_bounds__(256) void k_rfft_w(const float* __restrict__ x,
                                                unsigned* __restrict__ buf) {
    __shared__ float2 lds[32 * LROW];
    const int t = threadIdx.x;
    const size_t bdh = blockIdx.x;
    const float* xp = x + bdh * (size_t)(NDIM * CC);
    unsigned* op = buf + bdh * (size_t)(WR * CC);
    float2 tw[7];
    make_tw(t & 7, tw);
    for (int chunk = 0; chunk < 4; chunk++) {
        const int c0 = chunk * 32;
#pragma unroll
        for (int k = 0; k < 8; k++) {
            int i = k * 256 + t;
            int c = i & 31, w = i >> 5;
            float vv = xp[(size_t)w * CC + c0 + c] * ORTHO;
            lds[c * LROW + w] = make_float2(vv, 0.f);
        }
        __syncthreads();
        fft64_lds<-1>(&lds[(t >> 3) * LROW], t & 7, tw);
        __syncthreads();
        for (int i = t; i < WR * 32; i += 256) {
            int c = i & 31, kk = i >> 5;
            op[(size_t)kk * CC + c0 + c] = pack_c(lds[c * LROW + kk]);
        }
        __syncthreads();
    }
}

// ---------------- Passes 2,6: in-place complex FFT along H (strided axis).
template <int DIR>
__global__ __launch_bounds__(256) void k_fft_axis(unsigned* __restrict__ buf, int outerB,
                                                  long sA, long sB, long sAxis) {
    __shared__ float2 lds[32 * LROW];
    const int t = threadIdx.x;
    const long a = blockIdx.x / outerB;
    const long ob = blockIdx.x % outerB;
    unsigned* p0 = buf + a * sA + ob * sB;
    float2 tw[7];
    make_tw(t & 7, tw);
    for (int chunk = 0; chunk < 4; chunk++) {
        const int c0 = chunk * 32;
#pragma unroll
        for (int k = 0; k < 8; k++) {
            int i = k * 256 + t;
            int c = i & 31, n = i >> 5;
            lds[c * LROW + n] = unpack_c(p0[(long)n * sAxis + c0 + c]);
        }
        __syncthreads();
        fft64_lds<DIR>(&lds[(t >> 3) * LROW], t & 7, tw);
        __syncthreads();
#pragma unroll
        for (int k = 0; k < 8; k++) {
            int i = k * 256 + t;
            int c = i & 31, n = i >> 5;
            p0[(long)n * sAxis + c0 + c] = pack_c(lds[c * LROW + n]);
        }
        __syncthreads();
    }
}

// ---------------- Fused: FFT-D -> block-diag complex MLP + softshrink -> iFFT-D.
// One block per (b, h, wr, q). 128 threads, 32 channels x 64 d in LDS f32 (16.9 KB).
__global__ __launch_bounds__(128) void k_dmlp(unsigned* __restrict__ buf,
                                              const float* __restrict__ w1,
                                              const float* __restrict__ b1,
                                              const float* __restrict__ w2,
                                              const float* __restrict__ b2) {
    __shared__ float2 S[32 * LROW];  // [c local 0..31][d 0..63], pitch 66
    const int t = threadIdx.x;
    int id = blockIdx.x;
    const int q = id & 3; id >>= 2;        // channel quarter (32 ch)
    const int wr = id % WR; id /= WR;
    const int h = id % NDIM; id /= NDIM;
    const int b = id;
    unsigned* p0 = buf + (long)b * S_Bs + (long)h * S_Hs + (long)wr * S_WRs + q * 32;

    // load: 32 ch x 64 d. lane -> channel (contiguous 128B per 32-lane chunk)
    const int lc = t & 31;
    const int d0 = t >> 5;  // 0..3
#pragma unroll
    for (int k = 0; k < 16; k++) {
        int d = d0 + 4 * k;
        S[lc * LROW + d] = unpack_c(p0[(long)d * S_Ds + lc]);
    }
    float2 tw[7];
    make_tw(t & 7, tw);
    __syncthreads();

    // forward FFT along d: 16 groups of 8 threads, 32 rows -> 2 iterations
#pragma unroll 1
    for (int it = 0; it < 2; it++) {
        fft64_lds<-1>(&S[((t >> 3) + 16 * it) * LROW], t & 7, tw);
        __syncthreads();
    }

    // MLP: thread -> (freq point pt, local block bl). Weights via scalar path.
    {
        const int pt = t & 63;
        const int bl = t >> 6;  // 0..1, wave-uniform
        const int blk = __builtin_amdgcn_readfirstlane(2 * q + bl);  // 0..7
        const float* W1r = w1 + (size_t)blk * 256;
        const float* W1i = w1 + 2048 + (size_t)blk * 256;
        const float* W2r = w2 + (size_t)blk * 256;
        const float* W2i = w2 + 2048 + (size_t)blk * 256;

        float xr[16], xi[16];
#pragma unroll
        for (int i = 0; i < 16; i++) {
            float2 v = S[(bl * 16 + i) * LROW + pt];
            xr[i] = v.x;
            xi[i] = v.y;
        }
        float o1r[16], o1i[16];
#pragma unroll
        for (int o = 0; o < 16; o++) {
            o1r[o] = b1[blk * 16 + o];
            o1i[o] = b1[128 + blk * 16 + o];
        }
#pragma unroll
        for (int i = 0; i < 16; i++) {
#pragma unroll
            for (int o = 0; o < 16; o++) {
                float wr_ = W1r[i * 16 + o], wi_ = W1i[i * 16 + o];
                o1r[o] += xr[i] * wr_ - xi[i] * wi_;
                o1i[o] += xi[i] * wr_ + xr[i] * wi_;
            }
        }
#pragma unroll
        for (int o = 0; o < 16; o++) {
            o1r[o] = fmaxf(o1r[o], 0.f);
            o1i[o] = fmaxf(o1i[o], 0.f);
        }
        float o2r[16], o2i[16];
#pragma unroll
        for (int o = 0; o < 16; o++) {
            o2r[o] = b2[blk * 16 + o];
            o2i[o] = b2[128 + blk * 16 + o];
        }
#pragma unroll
        for (int i = 0; i < 16; i++) {
#pragma unroll
            for (int o = 0; o < 16; o++) {
                float wr_ = W2r[i * 16 + o], wi_ = W2i[i * 16 + o];
                o2r[o] += o1r[i] * wr_ - o1i[i] * wi_;
                o2i[o] += o1i[i] * wr_ + o1r[i] * wi_;
            }
        }
        __syncthreads();  // all MLP input reads done before overwriting S
#pragma unroll
        for (int o = 0; o < 16; o++) {
            float sr = o2r[o], si = o2i[o];
            sr = (sr > LAM) ? (sr - LAM) : ((sr < -LAM) ? (sr + LAM) : 0.f);
            si = (si > LAM) ? (si - LAM) : ((si < -LAM) ? (si + LAM) : 0.f);
            S[(bl * 16 + o) * LROW + pt] = make_float2(sr, si);
        }
    }
    __syncthreads();

    // inverse FFT along d, then store back packed
#pragma unroll 1
    for (int it = 0; it < 2; it++) {
        fft64_lds<1>(&S[((t >> 3) + 16 * it) * LROW], t & 7, tw);
        __syncthreads();
    }
#pragma unroll
    for (int k = 0; k < 16; k++) {
        int d = d0 + 4 * k;
        p0[(long)d * S_Ds + lc] = pack_c(S[lc * LROW + d]);
    }
}

// ---------------- Pass 7: irfft along W + residual.
__global__ __launch_bounds__(256) void k_irfft_w(const unsigned* __restrict__ buf,
                                                 const float* __restrict__ x,
                                                 float* __restrict__ out) {
    __shared__ float2 lds[32 * LROW];
    const int t = threadIdx.x;
    const size_t bdh = blockIdx.x;
    const unsigned* ip = buf + bdh * (size_t)(WR * CC);
    const float* xp = x + bdh * (size_t)(NDIM * CC);
    float* op = out + bdh * (size_t)(NDIM * CC);
    float2 tw[7];
    make_tw(t & 7, tw);
    for (int chunk = 0; chunk < 4; chunk++) {
        const int c0 = chunk * 32;
        for (int i = t; i < WR * 32; i += 256) {
            int c = i & 31, kk = i >> 5;
            lds[c * LROW + kk] = unpack_c(ip[(size_t)kk * CC + c0 + c]);
        }
        __syncthreads();
        // Hermitian fill: X[64-k] = conj(X[k]) for k=1..31
        for (int i = t; i < 31 * 32; i += 256) {
            int c = i & 31, kk = 33 + (i >> 5);
            float2 v = lds[c * LROW + (64 - kk)];
            lds[c * LROW + kk] = make_float2(v.x, -v.y);
        }
        __syncthreads();
        fft64_lds<1>(&lds[(t >> 3) * LROW], t & 7, tw);
        __syncthreads();
#pragma unroll
        for (int k = 0; k < 8; k++) {
            int i = k * 256 + t;
            int c = i & 31, w = i >> 5;
            size_t gi = (size_t)w * CC + c0 + c;
            op[gi] = lds[c * LROW + w].x * ORTHO + xp[gi];
        }
        __syncthreads();
    }
}

extern "C" void kernel_launch(void* const* d_in, const int* in_sizes, int n_in,
                              void* d_out, int out_size, void* d_ws, size_t ws_size,
                              hipStream_t stream) {
    const float* x = (const float*)d_in[0];
    const float* w1 = (const float*)d_in[1];
    const float* b1 = (const float*)d_in[2];
    const float* w2 = (const float*)d_in[3];
    const float* b2 = (const float*)d_in[4];
    float* out = (float*)d_out;
    unsigned* buf = (unsigned*)d_ws;  // B*D*H*WR*C u32 = 138.4 MB (L3-resident)

    // 1) rfft along W
    k_rfft_w<<<BB * NDIM * NDIM, 256, 0, stream>>>(x, buf);
    // 2) FFT along H
    k_fft_axis<-1><<<BB * NDIM * WR, 256, 0, stream>>>(buf, WR, S_Ds, S_WRs, S_Hs);
    // 3+4+5) fused FFT-D -> MLP -> iFFT-D (32 ch per block, 128 threads)
    k_dmlp<<<BB * NDIM * WR * 4, 128, 0, stream>>>(buf, w1, b1, w2, b2);
    // 6) inverse FFT along H
    k_fft_axis<1><<<BB * NDIM * WR, 256, 0, stream>>>(buf, WR, S_Ds, S_WRs, S_Hs);
    // 7) irfft along W + residual
    k_irfft_w<<<BB * NDIM * NDIM, 256, 0, stream>>>(buf, x, out);
}